// Round 3
// baseline (30235.101 us; speedup 1.0000x reference)
//
#include <hip/hip_runtime.h>
#include <hip/hip_bf16.h>
#include <cmath>

#define DIMC 192
#define NHEAD 6
#define HDIM 32
#define TDIM 128
#define HIDC 510
#define HID2C 1020
#define REDC 24
#define NB 4
#define NH 256
#define NW 256
#define HW 65536
#define NPB (DIMC*HW)
#define STRIP 16
#define TROWS 18

typedef unsigned short u16;

__device__ __forceinline__ float bf2f(u16 u){
  union { unsigned int i; float f; } v; v.i = ((unsigned int)u) << 16; return v.f;
}
__device__ __forceinline__ u16 f2bf(float f){
  union { float f; unsigned int i; } v; v.f = f;
  unsigned int i = v.i;
  return (u16)((i + 0x7FFFu + ((i >> 16) & 1u)) >> 16);
}

// ---------- transpose pin_w / pout_w to [c][o] layouts ----------
__global__ __launch_bounds__(256) void k_prep(const float* __restrict__ pin_w,
    const float* __restrict__ pout_w, float* __restrict__ pin_wT, float* __restrict__ pout_wT)
{
  int i = blockIdx.x*256 + threadIdx.x;
  if (i < HID2C*DIMC){ int o = i / DIMC, c = i % DIMC; pin_wT[(size_t)c*HID2C + o] = pin_w[i]; }
  if (i < DIMC*HIDC){ int o = i / HIDC, c = i % HIDC; pout_wT[(size_t)c*DIMC + o] = pout_w[i]; }
}

// ---------- per-batch sum/sumsq over x ----------
__global__ __launch_bounds__(256) void k_reduce(const float* __restrict__ x,
    double* __restrict__ sum, double* __restrict__ sq)
{
  int b = blockIdx.y;
  const float4* xb = (const float4*)(x + (size_t)b*NPB);
  float ls = 0.f, lq = 0.f;
  int n4 = NPB/4;
  for (int i = blockIdx.x*256 + threadIdx.x; i < n4; i += gridDim.x*256){
    float4 u = xb[i];
    ls += u.x+u.y+u.z+u.w; lq += u.x*u.x + u.y*u.y + u.z*u.z + u.w*u.w;
  }
  __shared__ float rs_[256], rq_[256];
  int tid = threadIdx.x;
  rs_[tid]=ls; rq_[tid]=lq; __syncthreads();
  for (int st=128; st>0; st>>=1){ if (tid<st){ rs_[tid]+=rs_[tid+st]; rq_[tid]+=rq_[tid+st]; } __syncthreads(); }
  if (tid==0){ atomicAdd(&sum[b], (double)rs_[0]); atomicAdd(&sq[b], (double)rq_[0]); }
}

__global__ void k_stats(const double* __restrict__ sum, const double* __restrict__ sq,
                        float* __restrict__ stats)
{
  int t = threadIdx.x;
  if (t < NB){
    double mu = sum[t] / (double)NPB;
    double var = sq[t] / (double)NPB - mu*mu;
    stats[2*t]   = (float)mu;
    stats[2*t+1] = (float)(1.0 / sqrt(var + 1e-5));
  }
}

// ---------- s = silu(temb@w1+b1)@w2+b2 ----------
__global__ __launch_bounds__(256) void k_svec(const float* __restrict__ temb,
    const float* __restrict__ w1, const float* __restrict__ b1,
    const float* __restrict__ w2, const float* __restrict__ b2, float* __restrict__ s)
{
  __shared__ float te[NB*TDIM];
  __shared__ float hid[NB*TDIM];
  int tid = threadIdx.x;
  for (int i = tid; i < NB*TDIM; i += 256) te[i] = temb[i];
  __syncthreads();
  for (int i = tid; i < NB*TDIM; i += 256){
    int b = i >> 7, j = i & 127;
    float a = b1[j];
    for (int c = 0; c < TDIM; c++) a += te[b*TDIM + c]*w1[c*TDIM + j];
    hid[i] = a / (1.f + expf(-a));
  }
  __syncthreads();
  for (int i = tid; i < NB*4*DIMC; i += 256){
    int b = i / 768, o = i % 768;
    float a = b2[o];
    for (int c = 0; c < TDIM; c++) a += hid[b*TDIM + c]*w2[c*768 + o];
    s[i] = a;
  }
}

// ---------- window attention with fused gn1+adawm on load ----------
// writes x1 = x + attn, accumulates gn2 stats
__global__ __launch_bounds__(256) void k_attn(
    const float* __restrict__ x0,
    const float* __restrict__ stats, const float* __restrict__ gg, const float* __restrict__ gb,
    const float* __restrict__ sv,
    const float* __restrict__ qkv_w, const float* __restrict__ qkv_b,
    const float* __restrict__ proj_w, const float* __restrict__ proj_b,
    float* __restrict__ x1out, double* __restrict__ gn2_sum, double* __restrict__ gn2_sq)
{
  __shared__ float xw[DIMC*16];      // [c][t]
  __shared__ float qkv[16*577];      // [t][o], pitch 577
  __shared__ float ao[16*200];       // [t][c], pitch 200
  __shared__ float rs_[256], rq_[256];

  int tid = threadIdx.x;
  int blk = blockIdx.x;
  int b  = blk >> 12;
  int wy = (blk >> 6) & 63;
  int wx = blk & 63;

  float mu = stats[2*b], rstd = stats[2*b+1];
  const float* sb = sv + b*768;

  // load 4x4 window as 4 quads/channel, apply gn1 + adawm inline
  for (int l = tid; l < DIMC*4; l += 256){
    int c = l >> 2, q = l & 3;
    int qy = q >> 1, qx = q & 1;
    const float* p = x0 + ((size_t)(b*DIMC + c)*NH + (wy*4 + qy*2))*NW + wx*4 + qx*2;
    float2 t0 = *(const float2*)p;
    float2 t1 = *(const float2*)(p + NW);
    float gc = gg[c], bc = gb[c];
    float n00 = (t0.x-mu)*rstd*gc + bc;
    float n01 = (t0.y-mu)*rstd*gc + bc;
    float n10 = (t1.x-mu)*rstd*gc + bc;
    float n11 = (t1.y-mu)*rstd*gc + bc;
    float ll = (n00+n01+n10+n11)*0.5f*sb[c];
    float hl = (n00-n10+n01-n11)*0.5f*sb[192+c];
    float lh = (n00+n10-n01-n11)*0.5f*sb[384+c];
    float hh = (n00-n10-n01+n11)*0.5f*sb[576+c];
    float* d = &xw[c*16 + qy*8 + qx*2];
    d[0] = (ll+hl+lh+hh)*0.5f;
    d[1] = (ll+hl-lh-hh)*0.5f;
    d[4] = (ll-hl+lh-hh)*0.5f;
    d[5] = (ll-hl-lh+hh)*0.5f;
  }
  __syncthreads();

  { // qkv: thread owns output columns o = tid, tid+256, tid+512
    float acc[3][16];
    int no = (tid < 64) ? 3 : 2;
    for (int k = 0; k < 3; k++)
      for (int t = 0; t < 16; t++) acc[k][t] = 0.f;
    for (int c = 0; c < DIMC; c++){
      float xv[16];
      #pragma unroll
      for (int t = 0; t < 16; t++) xv[t] = xw[c*16 + t];
      for (int k = 0; k < no; k++){
        float w = qkv_w[c*576 + tid + 256*k];
        #pragma unroll
        for (int t = 0; t < 16; t++) acc[k][t] += xv[t] * w;
      }
    }
    for (int k = 0; k < no; k++){
      int o = tid + 256*k;
      float bq = qkv_b[o];
      for (int t = 0; t < 16; t++) qkv[t*577 + o] = acc[k][t] + bq;
    }
  }
  __syncthreads();

  if (tid < 96){
    int h = tid >> 4, q = tid & 15;
    float sc[16]; float mx = -1e30f;
    for (int kt = 0; kt < 16; kt++){
      float d = 0.f;
      #pragma unroll
      for (int e = 0; e < HDIM; e++)
        d += qkv[q*577 + h*HDIM + e] * qkv[kt*577 + 192 + h*HDIM + e];
      d *= 0.17677669529663687f;
      sc[kt] = d; mx = fmaxf(mx, d);
    }
    float sum = 0.f;
    for (int kt = 0; kt < 16; kt++){ float e = expf(sc[kt]-mx); sc[kt]=e; sum+=e; }
    float inv = 1.f/sum;
    for (int e = 0; e < HDIM; e++){
      float a = 0.f;
      for (int kt = 0; kt < 16; kt++) a += sc[kt]*qkv[kt*577 + 384 + h*HDIM + e];
      ao[q*200 + h*HDIM + e] = a*inv;
    }
  }
  __syncthreads();

  float lsum = 0.f, lsq = 0.f;
  if (tid < DIMC){
    int o = tid;
    float acc[16];
    float pb = proj_b[o];
    #pragma unroll
    for (int t = 0; t < 16; t++) acc[t] = pb;
    for (int c = 0; c < DIMC; c++){
      float w = proj_w[c*DIMC + o];
      #pragma unroll
      for (int t = 0; t < 16; t++) acc[t] += ao[t*200 + c]*w;
    }
    #pragma unroll
    for (int t4 = 0; t4 < 4; t4++){
      int y = wy*4 + t4;
      size_t addr = ((size_t)(b*DIMC + o)*NH + y)*NW + wx*4;
      float4 xv = *(const float4*)&x0[addr];
      float4 ov;
      ov.x = xv.x + acc[t4*4+0];
      ov.y = xv.y + acc[t4*4+1];
      ov.z = xv.z + acc[t4*4+2];
      ov.w = xv.w + acc[t4*4+3];
      *(float4*)&x1out[addr] = ov;
      lsum += ov.x+ov.y+ov.z+ov.w;
      lsq  += ov.x*ov.x + ov.y*ov.y + ov.z*ov.z + ov.w*ov.w;
    }
  }
  rs_[tid] = lsum; rq_[tid] = lsq;
  __syncthreads();
  for (int st = 128; st > 0; st >>= 1){
    if (tid < st){ rs_[tid] += rs_[tid+st]; rq_[tid] += rq_[tid+st]; }
    __syncthreads();
  }
  if (tid == 0){
    atomicAdd(&gn2_sum[b], (double)rs_[0]);
    atomicAdd(&gn2_sq[b], (double)rq_[0]);
  }
}

// ---------- gdfn stage 1: fused gn2+adawm + pointwise 192->1020 into strip buffer T (bf16)
__global__ __launch_bounds__(256) void k_pin(
    const float* __restrict__ x1, const float* __restrict__ stats,
    const float* __restrict__ gg, const float* __restrict__ gb, const float* __restrict__ sv,
    const float* __restrict__ pin_wT, const float* __restrict__ pin_b,
    u16* __restrict__ T, int s)
{
  __shared__ float px[DIMC*16]; // [c][p]
  int tid = threadIdx.x;
  int xc = blockIdx.x, r = blockIdx.y, b = blockIdx.z;
  int y = s*STRIP - 1 + r;
  int x0 = xc*16;
  u16* Trow = T + ((size_t)(b*TROWS + r)*NW + x0)*HID2C;
  bool valid = (y >= 0) && (y < NH);
  if (!valid){
    for (int l = tid; l < 16*HID2C; l += 256) Trow[l] = 0;
    return;
  }
  float mu = stats[2*b], rstd = stats[2*b+1];
  const float* sb = sv + b*768;
  int ytop = y & ~1;
  bool istop = (y == ytop);
  for (int l = tid; l < DIMC*8; l += 256){
    int c = l >> 3, u = l & 7;
    const float* p = x1 + ((size_t)(b*DIMC + c)*NH + ytop)*NW + x0 + 2*u;
    float2 t0 = *(const float2*)p;
    float2 t1 = *(const float2*)(p + NW);
    float gc = gg[c], bc = gb[c];
    float n00 = (t0.x-mu)*rstd*gc + bc;
    float n01 = (t0.y-mu)*rstd*gc + bc;
    float n10 = (t1.x-mu)*rstd*gc + bc;
    float n11 = (t1.y-mu)*rstd*gc + bc;
    float ll = (n00+n01+n10+n11)*0.5f*sb[c];
    float hl = (n00-n10+n01-n11)*0.5f*sb[192+c];
    float lh = (n00+n10-n01-n11)*0.5f*sb[384+c];
    float hh = (n00-n10-n01+n11)*0.5f*sb[576+c];
    float v0, v1;
    if (istop){ v0 = (ll+hl+lh+hh)*0.5f; v1 = (ll+hl-lh-hh)*0.5f; }
    else      { v0 = (ll-hl+lh-hh)*0.5f; v1 = (ll-hl-lh+hh)*0.5f; }
    px[c*16 + 2*u]     = v0;
    px[c*16 + 2*u + 1] = v1;
  }
  __syncthreads();
  if (tid < 255){
    int o4 = tid*4;
    float4 bi = *(const float4*)&pin_b[o4];
    float acc[16][4];
    #pragma unroll
    for (int p = 0; p < 16; p++){ acc[p][0]=bi.x; acc[p][1]=bi.y; acc[p][2]=bi.z; acc[p][3]=bi.w; }
    for (int c = 0; c < DIMC; c++){
      float4 w = *(const float4*)&pin_wT[(size_t)c*HID2C + o4];
      #pragma unroll
      for (int p = 0; p < 16; p++){
        float xv = px[c*16 + p];
        acc[p][0] += xv*w.x; acc[p][1] += xv*w.y; acc[p][2] += xv*w.z; acc[p][3] += xv*w.w;
      }
    }
    for (int p = 0; p < 16; p++){
      ushort4 o; o.x=f2bf(acc[p][0]); o.y=f2bf(acc[p][1]); o.z=f2bf(acc[p][2]); o.w=f2bf(acc[p][3]);
      *(ushort4*)&Trow[(size_t)p*HID2C + o4] = o;
    }
  }
}

// ---------- gdfn stage 2: depthwise 3x3 + gelu-gate + pointwise 510->192 (channel-major G bf16)
__global__ __launch_bounds__(256) void k_dwgate(
    const u16* __restrict__ T, const float* __restrict__ pout_wT,
    const float* __restrict__ dw_w, const float* __restrict__ dw_b,
    const float* __restrict__ pout_b, u16* __restrict__ G,
    double* __restrict__ se_sum, int s)
{
  __shared__ float g[16][512];
  int tid = threadIdx.x;
  int xc = blockIdx.x, ry = blockIdx.y, b = blockIdx.z;
  int y = s*STRIP + ry;
  int x0 = xc*16;
  int r = ry + 1;
  if (tid < 255){
    for (int k = 0; k < 2; k++){
      int ch = 2*tid + k;
      int ch2 = ch + HIDC;
      float w1[9], w2[9];
      #pragma unroll
      for (int t9 = 0; t9 < 9; t9++){ w1[t9] = dw_w[ch*9+t9]; w2[t9] = dw_w[ch2*9+t9]; }
      float db1 = dw_b[ch], db2 = dw_b[ch2];
      for (int p = 0; p < 16; p++){
        int gx = x0 + p;
        float a1 = db1, a2 = db2;
        for (int dy = -1; dy <= 1; dy++){
          const u16* Tr = T + (size_t)(b*TROWS + r + dy)*NW*HID2C;
          for (int dx = -1; dx <= 1; dx++){
            int xx = gx + dx;
            if (xx < 0 || xx >= NW) continue;
            int wi = (dy+1)*3 + (dx+1);
            a1 += w1[wi]*bf2f(Tr[(size_t)xx*HID2C + ch]);
            a2 += w2[wi]*bf2f(Tr[(size_t)xx*HID2C + ch2]);
          }
        }
        float ge = 0.5f*a1*(1.f + erff(a1*0.70710678118654752f));
        g[p][ch] = ge*a2;
      }
    }
  }
  __syncthreads();
  if (tid < DIMC){
    int o = tid;
    float pb = pout_b[o];
    float acc[16];
    #pragma unroll
    for (int p = 0; p < 16; p++) acc[p] = pb;
    for (int c = 0; c < HIDC; c++){
      float w = pout_wT[(size_t)c*DIMC + o];
      #pragma unroll
      for (int p = 0; p < 16; p++) acc[p] += g[p][c]*w;
    }
    float lsum = 0.f;
    u16* Gp = G + ((size_t)(b*DIMC + o)*NH + y)*NW + x0;
    #pragma unroll
    for (int q4 = 0; q4 < 4; q4++){
      ushort4 ov;
      ov.x = f2bf(acc[q4*4+0]); ov.y = f2bf(acc[q4*4+1]);
      ov.z = f2bf(acc[q4*4+2]); ov.w = f2bf(acc[q4*4+3]);
      *(ushort4*)&Gp[q4*4] = ov;
    }
    #pragma unroll
    for (int p = 0; p < 16; p++) lsum += acc[p];
    atomicAdd(&se_sum[b*DIMC + o], (double)lsum);
  }
}

// ---------- SE gate vector ----------
__global__ __launch_bounds__(256) void k_se(const double* __restrict__ se_sum,
    const float* __restrict__ w1, const float* __restrict__ w2, float* __restrict__ sey)
{
  __shared__ float mean[NB*DIMC];
  __shared__ float hid[NB*REDC];
  int tid = threadIdx.x;
  for (int i = tid; i < NB*DIMC; i += 256) mean[i] = (float)(se_sum[i] * (1.0/(double)HW));
  __syncthreads();
  for (int i = tid; i < NB*REDC; i += 256){
    int b = i / REDC, rr = i % REDC;
    float a = 0.f;
    for (int c = 0; c < DIMC; c++) a += mean[b*DIMC + c]*w1[c*REDC + rr];
    hid[i] = fmaxf(a, 0.f);
  }
  __syncthreads();
  for (int i = tid; i < NB*DIMC; i += 256){
    int b = i / DIMC, o = i % DIMC;
    float a = 0.f;
    for (int rr = 0; rr < REDC; rr++) a += hid[b*REDC + rr]*w2[rr*DIMC + o];
    sey[i] = 1.f/(1.f + expf(-a));
  }
}

// ---------- final: out = x1 + G * sey  (channel-major, float4 RMW) ----------
__global__ __launch_bounds__(256) void k_final(const u16* __restrict__ G,
    const float* __restrict__ sey, float* __restrict__ xout)
{
  int i4 = blockIdx.x*256 + threadIdx.x;
  int cpix = i4 >> 14;              // b*DIMC + c
  float sc = sey[cpix];
  ushort4 gv = *(const ushort4*)&G[(size_t)i4*4];
  float4 xv = *(const float4*)&xout[(size_t)i4*4];
  float4 ov;
  ov.x = xv.x + bf2f(gv.x)*sc;
  ov.y = xv.y + bf2f(gv.y)*sc;
  ov.z = xv.z + bf2f(gv.z)*sc;
  ov.w = xv.w + bf2f(gv.w)*sc;
  *(float4*)&xout[(size_t)i4*4] = ov;
}

extern "C" void kernel_launch(void* const* d_in, const int* in_sizes, int n_in,
                              void* d_out, int out_size, void* d_ws, size_t ws_size,
                              hipStream_t stream)
{
  const float* x      = (const float*)d_in[0];
  const float* temb   = (const float*)d_in[1];
  const float* gn1_g  = (const float*)d_in[2];
  const float* gn1_b  = (const float*)d_in[3];
  const float* aw1_w1 = (const float*)d_in[4];
  const float* aw1_b1 = (const float*)d_in[5];
  const float* aw1_w2 = (const float*)d_in[6];
  const float* aw1_b2 = (const float*)d_in[7];
  const float* qkv_w  = (const float*)d_in[8];
  const float* qkv_b  = (const float*)d_in[9];
  const float* proj_w = (const float*)d_in[10];
  const float* proj_b = (const float*)d_in[11];
  const float* gn2_g  = (const float*)d_in[12];
  const float* gn2_b  = (const float*)d_in[13];
  const float* aw2_w1 = (const float*)d_in[14];
  const float* aw2_b1 = (const float*)d_in[15];
  const float* aw2_w2 = (const float*)d_in[16];
  const float* aw2_b2 = (const float*)d_in[17];
  const float* pin_w  = (const float*)d_in[18];
  const float* pin_b  = (const float*)d_in[19];
  const float* dw_w   = (const float*)d_in[20];
  const float* dw_b   = (const float*)d_in[21];
  const float* pout_w = (const float*)d_in[22];
  const float* pout_b = (const float*)d_in[23];
  const float* se_w1  = (const float*)d_in[24];
  const float* se_w2  = (const float*)d_in[25];

  unsigned char* ws = (unsigned char*)d_ws;
  size_t nElem = (size_t)NB*DIMC*HW;                       // 50331648
  u16* G  = (u16*)ws;                                      // gdfn out, channel-major bf16 (100.7 MB)
  u16* Tb = (u16*)(ws + nElem*2);                          // pin strip buffer bf16 (37.6 MB)
  size_t offD = nElem*2 + (size_t)NB*TROWS*NW*HID2C*2;
  double* gn1_sum = (double*)(ws + offD);
  double* gn1_sq  = gn1_sum + 4;
  double* gn2_sum = gn1_sum + 8;
  double* gn2_sq  = gn1_sum + 12;
  double* se_sum  = gn1_sum + 16;                          // 768 doubles
  float* fbase  = (float*)(ws + offD + 784*8);
  float* s1     = fbase;
  float* s2     = s1 + 3072;
  float* stats1 = s2 + 3072;
  float* stats2 = stats1 + 8;
  float* sey    = stats2 + 8;
  float* pin_wT  = sey + 768;                              // 192x1020 fp32
  float* pout_wT = pin_wT + (size_t)HID2C*DIMC;            // 510x192 fp32

  float* x1 = (float*)d_out;

  hipMemsetAsync(ws + offD, 0, 784*8, stream);
  k_prep<<<765, 256, 0, stream>>>(pin_w, pout_w, pin_wT, pout_wT);
  k_reduce<<<dim3(1024,4), 256, 0, stream>>>(x, gn1_sum, gn1_sq);
  k_stats<<<1, 64, 0, stream>>>(gn1_sum, gn1_sq, stats1);
  k_svec<<<1, 256, 0, stream>>>(temb, aw1_w1, aw1_b1, aw1_w2, aw1_b2, s1);
  k_svec<<<1, 256, 0, stream>>>(temb, aw2_w1, aw2_b1, aw2_w2, aw2_b2, s2);
  k_attn<<<16384, 256, 0, stream>>>(x, stats1, gn1_g, gn1_b, s1,
                                    qkv_w, qkv_b, proj_w, proj_b, x1, gn2_sum, gn2_sq);
  k_stats<<<1, 64, 0, stream>>>(gn2_sum, gn2_sq, stats2);
  for (int s = 0; s < 16; s++){
    k_pin<<<dim3(16, TROWS, 4), 256, 0, stream>>>(x1, stats2, gn2_g, gn2_b, s2,
                                                  pin_wT, pin_b, Tb, s);
    k_dwgate<<<dim3(16, STRIP, 4), 256, 0, stream>>>(Tb, pout_wT, dw_w, dw_b, pout_b, G, se_sum, s);
  }
  k_se<<<1, 256, 0, stream>>>(se_sum, se_w1, se_w2, sey);
  k_final<<<49152, 256, 0, stream>>>(G, sey, x1);
}